// Round 3
// baseline (4245.862 us; speedup 1.0000x reference)
//
#include <hip/hip_runtime.h>

#define TLEN 256
#define DD 8
#define HH 128
#define BR 16
#define NTHREADS 512

typedef __attribute__((ext_vector_type(8))) _Float16 half8;
typedef __attribute__((ext_vector_type(4))) float f32x4;

#define LOSCALE 65536.0f
#define LOINV   (1.0f/65536.0f)

static __device__ __forceinline__ float tanh_fast(float x){
  float cx = fminf(fmaxf(x, -9.01f), 9.01f);
  float e = __builtin_amdgcn_exp2f(cx * 2.885390081777927f); // exp(2x)
  return 1.0f - 2.0f * __builtin_amdgcn_rcpf(e + 1.0f);
}

static __device__ __forceinline__ void split_store(float v, unsigned short* hiA, unsigned short* loA, unsigned byte){
  _Float16 h = (_Float16)v;
  _Float16 l = (_Float16)(v - (float)h);   // activations: lo unscaled (normal range)
  *(_Float16*)((char*)hiA + byte) = h;
  *(_Float16*)((char*)loA + byte) = l;
}

// ---- pack W2 into MFMA B-fragment order: hi (unscaled) + lo (x65536), fp16.
// frag f = (w*8+ct)*4+kt, lane l holds W2[kt*32+(l>>4)*8+j][w*128+ct*16+(l&15)], j=0..7
__global__ void pack_w2_kernel(const float* __restrict__ W2, half8* __restrict__ ws){
  int gid = blockIdx.x * 256 + threadIdx.x;   // 64 blocks x 256 = 16384 = 256 frags x 64 lanes
  int l = gid & 63;
  int f = gid >> 6;                           // 0..255
  int kt = f & 3, ct = (f >> 2) & 7, w = f >> 5;
  int col = w*128 + ct*16 + (l & 15);
  int kb  = kt*32 + (l >> 4)*8;
  half8 vh, vl;
  #pragma unroll
  for (int j = 0; j < 8; j++){
    float v = W2[(kb + j)*1024 + col];
    _Float16 h = (_Float16)v;
    vh[j] = h;
    vl[j] = (_Float16)((v - (float)h) * LOSCALE);
  }
  ws[f*64 + l] = vh;            // hi region: frags [0,256)
  ws[(256 + f)*64 + l] = vl;    // lo region
}

// One block = 16 batch rows for the whole T recurrence. 8 waves.
// Wave w owns cols [16w,16w+16) of h1/h2 and cols [128w,128w+128) of GEMM3.
__global__ __launch_bounds__(NTHREADS, 2) void ncde_kernel(
    const float* __restrict__ x, const float* __restrict__ Win, const float* __restrict__ bin,
    const float* __restrict__ W0, const float* __restrict__ b0v, const float* __restrict__ W1,
    const float* __restrict__ b1v, const float* __restrict__ W2, const float* __restrict__ b2v,
    const half8* __restrict__ wsw2, float* __restrict__ out)
{
  __shared__ half8 w0fh[2048], w0fl[2048];   // 32+32 KB  W0 hi / lo(x65536)
  __shared__ half8 w1fh[2048], w1fl[2048];   // 32+32 KB
  __shared__ unsigned short zhh[2048], zhl[2048];  // fp16 z hi/lo, XOR-swizzled
  __shared__ unsigned short h1h[2048], h1l[2048];
  __shared__ unsigned short h2h[2048], h2l[2048];  // 6 x 4 KB
  __shared__ float b2lds[1024];              // 4 KB

  const int t    = threadIdx.x;
  const int lane = t & 63;
  const int w    = t >> 6;        // wave 0..7
  const int lg   = lane >> 4;     // lane group 0..3
  const int ln   = lane & 15;
  const int b0blk = blockIdx.x * BR;

  // ---- one-time: W0/W1 -> LDS hi/lo B-fragments
  for (int s = t; s < 4096; s += NTHREADS){
    int which = s >> 11;
    int s2 = s & 2047;
    int la = s2 & 63;
    int nt = (s2 >> 6) & 7;
    int kt = s2 >> 9;
    const float* Wsrc = which ? W1 : W0;
    int kb  = kt*32 + (la >> 4)*8;
    int col = nt*16 + (la & 15);
    half8 vh, vl;
    #pragma unroll
    for (int j = 0; j < 8; j++){
      float v = Wsrc[(kb + j)*HH + col];
      _Float16 h = (_Float16)v;
      vh[j] = h;
      vl[j] = (_Float16)((v - (float)h) * LOSCALE);
    }
    if (which){ w1fh[s2] = vh; w1fl[s2] = vl; } else { w0fh[s2] = vh; w0fl[s2] = vl; }
  }
  for (int s = t; s < 1024; s += NTHREADS) b2lds[s] = b2v[s];

  // ---- one-time: W2 hi fragments -> registers (from packed ws)
  half8 w2f[8][4];
  #pragma unroll
  for (int ct = 0; ct < 8; ct++)
    #pragma unroll
    for (int kt = 0; kt < 4; kt++)
      w2f[ct][kt] = wsw2[((w*8 + ct)*4 + kt)*64 + lane];
  const half8* wsL = wsw2 + 256*64;

  const float b0r = b0v[w*16 + ln];
  const float w0L = W0[128*HH + w*16 + ln];   // time-channel row (exact fp32)
  const float b1r = b1v[w*16 + ln];

  float xprev[4];
  #pragma unroll
  for (int r = 0; r < 4; r++)
    xprev[r] = x[(size_t)(b0blk + lg*4 + r)*(TLEN*DD) + (lane & 7)];

  // ---- z0 = x[:,0,:] @ Win + bin (exact fp32), stored as fp16 hi/lo
  for (int o = t; o < BR*HH; o += NTHREADS){
    int br = o >> 7, h = o & 127;
    float acc = bin[h];
    const float* xb = x + (size_t)(b0blk + br)*(TLEN*DD);
    #pragma unroll
    for (int d = 0; d < DD; d++) acc += xb[d] * Win[d*HH + h];
    unsigned byte = (unsigned)br*256u + (((unsigned)h*2u) ^ (((unsigned)(br & 7)) << 4));
    split_store(acc, zhh, zhl, byte);
  }
  __syncthreads();

  // z accumulator in registers: zreg[ct][r] = z[b=lg*4+r][h=16w+2ct+bit3]
  float zreg[8][4];
  #pragma unroll
  for (int ct = 0; ct < 8; ct++){
    int h = w*16 + ct*2 + ((lane >> 3) & 1);
    #pragma unroll
    for (int r = 0; r < 4; r++){
      int br = lg*4 + r;
      unsigned byte = (unsigned)br*256u + (((unsigned)h*2u) ^ (((unsigned)(br & 7)) << 4));
      zreg[ct][r] = (float)*(_Float16*)((char*)zhh + byte) + (float)*(_Float16*)((char*)zhl + byte);
    }
  }

  // out[:,0,:]
  for (int o = t; o < BR*HH; o += NTHREADS){
    int br = o >> 7, h = o & 127;
    unsigned byte = (unsigned)br*256u + (((unsigned)h*2u) ^ (((unsigned)(br & 7)) << 4));
    out[(size_t)(b0blk + br)*(TLEN*HH) + h] =
        (float)*(_Float16*)((char*)zhh + byte) + (float)*(_Float16*)((char*)zhl + byte);
  }

  const float inv = 1.0f / 255.0f;

  for (int k = 0; k < TLEN - 1; k++){
    float tk = (float)k * inv;

    float xn[4];
    #pragma unroll
    for (int r = 0; r < 4; r++)
      xn[r] = x[(size_t)(b0blk + lg*4 + r)*(TLEN*DD) + (size_t)(k + 1)*DD + (lane & 7)];

    // ---- GEMM1: h1 = relu([z,t] @ W0 + b0)
    f32x4 acc  = {0.f,0.f,0.f,0.f};
    f32x4 acc2 = {0.f,0.f,0.f,0.f};
    #pragma unroll
    for (int kt = 0; kt < 4; kt++){
      unsigned byte = (unsigned)ln*256u + ((((unsigned)(kt*4 + lg))*16u) ^ (((unsigned)(ln & 7)) << 4));
      half8 ahi = *(const half8*)((const char*)zhh + byte);
      half8 alo = *(const half8*)((const char*)zhl + byte);
      half8 bh = w0fh[(kt*8 + w)*64 + lane];
      half8 bl = w0fl[(kt*8 + w)*64 + lane];
      acc  = __builtin_amdgcn_mfma_f32_16x16x32_f16(ahi, bh, acc,  0, 0, 0);
      acc  = __builtin_amdgcn_mfma_f32_16x16x32_f16(alo, bh, acc,  0, 0, 0);
      acc2 = __builtin_amdgcn_mfma_f32_16x16x32_f16(ahi, bl, acc2, 0, 0, 0);
    }
    {
      float c0 = b0r + tk * w0L;
      #pragma unroll
      for (int r = 0; r < 4; r++){
        float v = fmaxf(acc[r] + acc2[r]*LOINV + c0, 0.0f);
        int row = lg*4 + r;
        unsigned byte = (unsigned)row*256u + ((((unsigned)(w*16 + ln))*2u) ^ (((unsigned)(row & 7)) << 4));
        split_store(v, h1h, h1l, byte);
      }
    }
    __syncthreads(); // B1

    // ---- GEMM2: h2 = relu(h1 @ W1 + b1)
    acc  = (f32x4){0.f,0.f,0.f,0.f};
    acc2 = (f32x4){0.f,0.f,0.f,0.f};
    #pragma unroll
    for (int kt = 0; kt < 4; kt++){
      unsigned byte = (unsigned)ln*256u + ((((unsigned)(kt*4 + lg))*16u) ^ (((unsigned)(ln & 7)) << 4));
      half8 ahi = *(const half8*)((const char*)h1h + byte);
      half8 alo = *(const half8*)((const char*)h1l + byte);
      half8 bh = w1fh[(kt*8 + w)*64 + lane];
      half8 bl = w1fl[(kt*8 + w)*64 + lane];
      acc  = __builtin_amdgcn_mfma_f32_16x16x32_f16(ahi, bh, acc,  0, 0, 0);
      acc  = __builtin_amdgcn_mfma_f32_16x16x32_f16(alo, bh, acc,  0, 0, 0);
      acc2 = __builtin_amdgcn_mfma_f32_16x16x32_f16(ahi, bl, acc2, 0, 0, 0);
    }
    #pragma unroll
    for (int r = 0; r < 4; r++){
      float v = fmaxf(acc[r] + acc2[r]*LOINV + b1r, 0.0f);
      int row = lg*4 + r;
      unsigned byte = (unsigned)row*256u + ((((unsigned)(w*16 + ln))*2u) ^ (((unsigned)(row & 7)) << 4));
      split_store(v, h2h, h2l, byte);
    }
    // prefetch ct=0 W2-lo frags (global; independent of LDS barrier)
    half8 wl[4];
    #pragma unroll
    for (int kt = 0; kt < 4; kt++) wl[kt] = wsL[((w*8 + 0)*4 + kt)*64 + lane];
    __syncthreads(); // B2

    // ---- GEMM3 + tanh + einsum over d (= lane&7)
    half8 ahh[4], ahl[4];
    #pragma unroll
    for (int kt = 0; kt < 4; kt++){
      unsigned byte = (unsigned)ln*256u + ((((unsigned)(kt*4 + lg))*16u) ^ (((unsigned)(ln & 7)) << 4));
      ahh[kt] = *(const half8*)((const char*)h2h + byte);
      ahl[kt] = *(const half8*)((const char*)h2l + byte);
    }
    float dxr[4];
    #pragma unroll
    for (int r = 0; r < 4; r++){ dxr[r] = xn[r] - xprev[r]; xprev[r] = xn[r]; }

    #pragma unroll
    for (int ct = 0; ct < 8; ct++){
      f32x4 a3  = {0.f,0.f,0.f,0.f};
      f32x4 a3c = {0.f,0.f,0.f,0.f};
      #pragma unroll
      for (int kt = 0; kt < 4; kt++){
        a3 = __builtin_amdgcn_mfma_f32_16x16x32_f16(ahh[kt], w2f[ct][kt], a3, 0, 0, 0);
        a3 = __builtin_amdgcn_mfma_f32_16x16x32_f16(ahl[kt], w2f[ct][kt], a3, 0, 0, 0);
      }
      #pragma unroll
      for (int kt = 0; kt < 4; kt++)
        a3c = __builtin_amdgcn_mfma_f32_16x16x32_f16(ahh[kt], wl[kt], a3c, 0, 0, 0);
      // issue next ct's W2-lo loads (covered by tanh + next ct's hi-MFMAs)
      if (ct < 7){
        #pragma unroll
        for (int kt = 0; kt < 4; kt++) wl[kt] = wsL[((w*8 + ct + 1)*4 + kt)*64 + lane];
      }
      float b2c = b2lds[w*128 + ct*16 + ln];
      #pragma unroll
      for (int r = 0; r < 4; r++){
        float p = tanh_fast(a3[r] + a3c[r]*LOINV + b2c) * dxr[r];
        p += __shfl_xor(p, 1, 64);
        p += __shfl_xor(p, 2, 64);
        p += __shfl_xor(p, 4, 64);
        zreg[ct][r] += p;   // sum over d
      }
    }

    if ((lane & 7) == 0){
      #pragma unroll
      for (int ct = 0; ct < 8; ct++){
        int h = w*16 + ct*2 + ((lane >> 3) & 1);
        #pragma unroll
        for (int r = 0; r < 4; r++){
          int br = lg*4 + r;
          unsigned byte = (unsigned)br*256u + (((unsigned)h*2u) ^ (((unsigned)(br & 7)) << 4));
          split_store(zreg[ct][r], zhh, zhl, byte);
        }
      }
    }
    __syncthreads(); // B3

    // out[:,k+1,:] — coalesced, reconstructed fp32 = hi + lo
    {
      const size_t tb = (size_t)(k + 1)*HH;
      for (int o = t; o < BR*HH; o += NTHREADS){
        int br = o >> 7, h = o & 127;
        unsigned byte = (unsigned)br*256u + (((unsigned)h*2u) ^ (((unsigned)(br & 7)) << 4));
        out[(size_t)(b0blk + br)*(TLEN*HH) + tb + h] =
            (float)*(_Float16*)((char*)zhh + byte) + (float)*(_Float16*)((char*)zhl + byte);
      }
    }
  }
}

extern "C" void kernel_launch(void* const* d_in, const int* in_sizes, int n_in,
                              void* d_out, int out_size, void* d_ws, size_t ws_size,
                              hipStream_t stream) {
  const float* x   = (const float*)d_in[0];
  const float* Win = (const float*)d_in[1];
  const float* bin = (const float*)d_in[2];
  const float* W0  = (const float*)d_in[3];
  const float* b0  = (const float*)d_in[4];
  const float* W1  = (const float*)d_in[5];
  const float* b1  = (const float*)d_in[6];
  const float* W2  = (const float*)d_in[7];
  const float* b2  = (const float*)d_in[8];
  float* out = (float*)d_out;
  half8* wsw2 = (half8*)d_ws;   // 512 KB: 256 hi frags + 256 lo frags

  pack_w2_kernel<<<dim3(64), dim3(256), 0, stream>>>(W2, wsw2);
  ncde_kernel<<<dim3(1024 / BR), dim3(NTHREADS), 0, stream>>>(
      x, Win, bin, W0, b0, W1, b1, W2, b2, wsw2, out);
}

// Round 4
// 2249.628 us; speedup vs baseline: 1.8874x; 1.8874x over previous
//
#include <hip/hip_runtime.h>

#define TLEN 256
#define DD 8
#define HH 128
#define BR 16
#define NTHREADS 512

typedef __attribute__((ext_vector_type(8))) _Float16 half8;
typedef __attribute__((ext_vector_type(4))) float f32x4;

#define LOSCALE 65536.0f
#define LOINV   (1.0f/65536.0f)

static __device__ __forceinline__ float tanh_fast(float x){
  float cx = fminf(fmaxf(x, -9.01f), 9.01f);
  float e = __builtin_amdgcn_exp2f(cx * 2.885390081777927f); // exp(2x)
  return 1.0f - 2.0f * __builtin_amdgcn_rcpf(e + 1.0f);
}

static __device__ __forceinline__ void split_store(float v, unsigned short* hiA, unsigned short* loA, unsigned byte){
  _Float16 h = (_Float16)v;
  _Float16 l = (_Float16)(v - (float)h);   // activations: lo unscaled (normal range)
  *(_Float16*)((char*)hiA + byte) = h;
  *(_Float16*)((char*)loA + byte) = l;
}

// ---- pack W2 into MFMA fragment order: hi (unscaled) + lo (x65536), fp16.
// frag f = (w*8+ct)*4+kt, lane l holds W2[kt*32+(l>>4)*8+j][w*128+ct*16+(l&15)], j=0..7
// (this lane mapping serves BOTH as B-frag of W2 and as A-frag of W2^T)
__global__ void pack_w2_kernel(const float* __restrict__ W2, half8* __restrict__ ws){
  int gid = blockIdx.x * 256 + threadIdx.x;   // 64 blocks x 256 = 16384 = 256 frags x 64 lanes
  int l = gid & 63;
  int f = gid >> 6;                           // 0..255
  int kt = f & 3, ct = (f >> 2) & 7, w = f >> 5;
  int col = w*128 + ct*16 + (l & 15);
  int kb  = kt*32 + (l >> 4)*8;
  half8 vh, vl;
  #pragma unroll
  for (int j = 0; j < 8; j++){
    float v = W2[(kb + j)*1024 + col];
    _Float16 h = (_Float16)v;
    vh[j] = h;
    vl[j] = (_Float16)((v - (float)h) * LOSCALE);
  }
  ws[f*64 + l] = vh;            // hi region: frags [0,256)
  ws[(256 + f)*64 + l] = vl;    // lo region
}

// One block = 16 batch rows for the whole T recurrence. 8 waves.
// Wave w owns cols [16w,16w+16) of h1/h2 and rows (c) [128w,128w+128) of G3^T.
__global__ __launch_bounds__(NTHREADS, 2) void ncde_kernel(
    const float* __restrict__ x, const float* __restrict__ Win, const float* __restrict__ bin,
    const float* __restrict__ W0, const float* __restrict__ b0v, const float* __restrict__ W1,
    const float* __restrict__ b1v, const float* __restrict__ W2, const float* __restrict__ b2v,
    const half8* __restrict__ wsw2, float* __restrict__ out)
{
  __shared__ half8 w0fh[2048], w0fl[2048];   // 32+32 KB  W0 hi / lo(x65536)
  __shared__ half8 w1fh[2048], w1fl[2048];   // 32+32 KB
  __shared__ unsigned short zhh[2048], zhl[2048];  // fp16 z hi/lo, XOR-swizzled
  __shared__ unsigned short h1h[2048], h1l[2048];
  __shared__ unsigned short h2h[2048], h2l[2048];  // 6 x 4 KB
  __shared__ f32x4 b2lds4[256];              // 4 KB

  const int t    = threadIdx.x;
  const int lane = t & 63;
  const int w    = t >> 6;        // wave 0..7
  const int lg   = lane >> 4;     // lane group 0..3
  const int ln   = lane & 15;
  const int b0blk = blockIdx.x * BR;
  const int dbase = (lg & 1) * 4; // d-half this lane's regs cover in G3^T epilogue

  // ---- one-time: W0/W1 -> LDS hi/lo B-fragments
  for (int s = t; s < 4096; s += NTHREADS){
    int which = s >> 11;
    int s2 = s & 2047;
    int la = s2 & 63;
    int nt = (s2 >> 6) & 7;
    int kt = s2 >> 9;
    const float* Wsrc = which ? W1 : W0;
    int kb  = kt*32 + (la >> 4)*8;
    int col = nt*16 + (la & 15);
    half8 vh, vl;
    #pragma unroll
    for (int j = 0; j < 8; j++){
      float v = Wsrc[(kb + j)*HH + col];
      _Float16 h = (_Float16)v;
      vh[j] = h;
      vl[j] = (_Float16)((v - (float)h) * LOSCALE);
    }
    if (which){ w1fh[s2] = vh; w1fl[s2] = vl; } else { w0fh[s2] = vh; w0fl[s2] = vl; }
  }
  for (int s = t; s < 1024; s += NTHREADS) ((float*)b2lds4)[s] = b2v[s];

  // ---- one-time: W2 hi fragments -> registers (from packed ws)
  half8 w2f[8][4];
  #pragma unroll
  for (int ct = 0; ct < 8; ct++)
    #pragma unroll
    for (int kt = 0; kt < 4; kt++)
      w2f[ct][kt] = wsw2[((w*8 + ct)*4 + kt)*64 + lane];
  const half8* wsL = wsw2 + 256*64;

  const float b0r = b0v[w*16 + ln];
  const float w0L = W0[128*HH + w*16 + ln];   // time-channel row (exact fp32)
  const float b1r = b1v[w*16 + ln];

  // xprev: this lane's 4 dx-channels of batch row b=ln
  f32x4 xprev = *(const f32x4*)(x + (size_t)(b0blk + ln)*(TLEN*DD) + dbase);

  // ---- z0 = x[:,0,:] @ Win + bin (exact fp32), stored as fp16 hi/lo
  for (int o = t; o < BR*HH; o += NTHREADS){
    int br = o >> 7, h = o & 127;
    float acc = bin[h];
    const float* xb = x + (size_t)(b0blk + br)*(TLEN*DD);
    #pragma unroll
    for (int d = 0; d < DD; d++) acc += xb[d] * Win[d*HH + h];
    unsigned byte = (unsigned)br*256u + (((unsigned)h*2u) ^ (((unsigned)(br & 7)) << 4));
    split_store(acc, zhh, zhl, byte);
  }
  __syncthreads();

  // z accumulator: zreg[ct] = z[b=ln][h = w*16 + ct*2 + (lg>>1)]  (duplicated across lg-pairs)
  float zreg[8];
  #pragma unroll
  for (int ct = 0; ct < 8; ct++){
    int h = w*16 + ct*2 + (lg >> 1);
    unsigned byte = (unsigned)ln*256u + (((unsigned)h*2u) ^ (((unsigned)(ln & 7)) << 4));
    zreg[ct] = (float)*(_Float16*)((char*)zhh + byte) + (float)*(_Float16*)((char*)zhl + byte);
  }

  // out[:,0,:] + per-thread out pointers (4 rows each, advanced by HH per step)
  float* outp[4];
  #pragma unroll
  for (int i = 0; i < 4; i++){
    int o = t + i*NTHREADS;
    int br = o >> 7, h = o & 127;
    outp[i] = out + (size_t)(b0blk + br)*(TLEN*HH) + h;
    unsigned byte = (unsigned)br*256u + (((unsigned)h*2u) ^ (((unsigned)(br & 7)) << 4));
    *outp[i] = (float)*(_Float16*)((char*)zhh + byte) + (float)*(_Float16*)((char*)zhl + byte);
    outp[i] += HH;
  }

  const float inv = 1.0f / 255.0f;

  for (int k = 0; k < TLEN - 1; k++){
    float tk = (float)k * inv;

    f32x4 xn = *(const f32x4*)(x + (size_t)(b0blk + ln)*(TLEN*DD) + (size_t)(k + 1)*DD + dbase);

    // ---- GEMM1: h1 = relu([z,t] @ W0 + b0)  (3 parallel 4-deep MFMA chains)
    f32x4 acch = {0.f,0.f,0.f,0.f}, accl = {0.f,0.f,0.f,0.f}, acc2 = {0.f,0.f,0.f,0.f};
    #pragma unroll
    for (int kt = 0; kt < 4; kt++){
      unsigned byte = (unsigned)ln*256u + ((((unsigned)(kt*4 + lg))*16u) ^ (((unsigned)(ln & 7)) << 4));
      half8 ahi = *(const half8*)((const char*)zhh + byte);
      half8 alo = *(const half8*)((const char*)zhl + byte);
      half8 bh = w0fh[(kt*8 + w)*64 + lane];
      half8 bl = w0fl[(kt*8 + w)*64 + lane];
      acch = __builtin_amdgcn_mfma_f32_16x16x32_f16(ahi, bh, acch, 0, 0, 0);
      accl = __builtin_amdgcn_mfma_f32_16x16x32_f16(alo, bh, accl, 0, 0, 0);
      acc2 = __builtin_amdgcn_mfma_f32_16x16x32_f16(ahi, bl, acc2, 0, 0, 0);
    }
    {
      float c0 = b0r + tk * w0L;
      #pragma unroll
      for (int r = 0; r < 4; r++){
        float v = fmaxf(acch[r] + accl[r] + acc2[r]*LOINV + c0, 0.0f);
        int row = lg*4 + r;
        unsigned byte = (unsigned)row*256u + ((((unsigned)(w*16 + ln))*2u) ^ (((unsigned)(row & 7)) << 4));
        split_store(v, h1h, h1l, byte);
      }
    }
    __syncthreads(); // B1

    // ---- GEMM2: h2 = relu(h1 @ W1 + b1)
    acch = (f32x4){0.f,0.f,0.f,0.f}; accl = (f32x4){0.f,0.f,0.f,0.f}; acc2 = (f32x4){0.f,0.f,0.f,0.f};
    #pragma unroll
    for (int kt = 0; kt < 4; kt++){
      unsigned byte = (unsigned)ln*256u + ((((unsigned)(kt*4 + lg))*16u) ^ (((unsigned)(ln & 7)) << 4));
      half8 ahi = *(const half8*)((const char*)h1h + byte);
      half8 alo = *(const half8*)((const char*)h1l + byte);
      half8 bh = w1fh[(kt*8 + w)*64 + lane];
      half8 bl = w1fl[(kt*8 + w)*64 + lane];
      acch = __builtin_amdgcn_mfma_f32_16x16x32_f16(ahi, bh, acch, 0, 0, 0);
      accl = __builtin_amdgcn_mfma_f32_16x16x32_f16(alo, bh, accl, 0, 0, 0);
      acc2 = __builtin_amdgcn_mfma_f32_16x16x32_f16(ahi, bl, acc2, 0, 0, 0);
    }
    #pragma unroll
    for (int r = 0; r < 4; r++){
      float v = fmaxf(acch[r] + accl[r] + acc2[r]*LOINV + b1r, 0.0f);
      int row = lg*4 + r;
      unsigned byte = (unsigned)row*256u + ((((unsigned)(w*16 + ln))*2u) ^ (((unsigned)(row & 7)) << 4));
      split_store(v, h2h, h2l, byte);
    }
    // prefetch ct=0 W2-lo frags (global; independent of LDS barrier)
    half8 wl[4];
    #pragma unroll
    for (int kt = 0; kt < 4; kt++) wl[kt] = wsL[((w*8 + 0)*4 + kt)*64 + lane];
    __syncthreads(); // B2

    // ---- GEMM3 transposed: G3^T = W2^T (A, regs) x h2^T (B, LDS — same read as A-frag)
    half8 ahh[4], ahl[4];
    #pragma unroll
    for (int kt = 0; kt < 4; kt++){
      unsigned byte = (unsigned)ln*256u + ((((unsigned)(kt*4 + lg))*16u) ^ (((unsigned)(ln & 7)) << 4));
      ahh[kt] = *(const half8*)((const char*)h2h + byte);
      ahl[kt] = *(const half8*)((const char*)h2l + byte);
    }
    f32x4 dxr = xn - xprev;
    xprev = xn;

    #pragma unroll
    for (int ct = 0; ct < 8; ct++){
      f32x4 b2q = b2lds4[w*32 + ct*4 + lg];  // broadcast within 16 lanes, conflict-free
      f32x4 a3h = {0.f,0.f,0.f,0.f}, a3l = {0.f,0.f,0.f,0.f}, a3c = {0.f,0.f,0.f,0.f};
      #pragma unroll
      for (int kt = 0; kt < 4; kt++)
        a3h = __builtin_amdgcn_mfma_f32_16x16x32_f16(w2f[ct][kt], ahh[kt], a3h, 0, 0, 0);
      #pragma unroll
      for (int kt = 0; kt < 4; kt++)
        a3l = __builtin_amdgcn_mfma_f32_16x16x32_f16(w2f[ct][kt], ahl[kt], a3l, 0, 0, 0);
      #pragma unroll
      for (int kt = 0; kt < 4; kt++)
        a3c = __builtin_amdgcn_mfma_f32_16x16x32_f16(wl[kt], ahh[kt], a3c, 0, 0, 0);
      // issue next ct's W2-lo loads (covered by epilogue + next ct's MFMAs)
      if (ct < 7){
        #pragma unroll
        for (int kt = 0; kt < 4; kt++) wl[kt] = wsL[((w*8 + ct + 1)*4 + kt)*64 + lane];
      }
      // lane holds c = w*128 + ct*16 + lg*4 + r  (h = w*16+ct*2+(lg>>1), d = dbase + r)
      float s = 0.0f;
      #pragma unroll
      for (int r = 0; r < 4; r++){
        float val = tanh_fast(a3h[r] + a3l[r] + a3c[r]*LOINV + b2q[r]);
        s += val * dxr[r];
      }
      s += __shfl_xor(s, 16, 64);   // combine the two d-halves (lg pair)
      zreg[ct] += s;
    }

    // z writeback: lanes with even lg own distinct (b,h)
    if ((lg & 1) == 0){
      #pragma unroll
      for (int ct = 0; ct < 8; ct++){
        int h = w*16 + ct*2 + (lg >> 1);
        unsigned byte = (unsigned)ln*256u + (((unsigned)h*2u) ^ (((unsigned)(ln & 7)) << 4));
        split_store(zreg[ct], zhh, zhl, byte);
      }
    }
    __syncthreads(); // B3

    // out[:,k+1,:] — coalesced, reconstructed fp32 = hi + lo
    #pragma unroll
    for (int i = 0; i < 4; i++){
      int o = t + i*NTHREADS;
      int br = o >> 7, h = o & 127;
      unsigned byte = (unsigned)br*256u + (((unsigned)h*2u) ^ (((unsigned)(br & 7)) << 4));
      *outp[i] = (float)*(_Float16*)((char*)zhh + byte) + (float)*(_Float16*)((char*)zhl + byte);
      outp[i] += HH;
    }
  }
}

extern "C" void kernel_launch(void* const* d_in, const int* in_sizes, int n_in,
                              void* d_out, int out_size, void* d_ws, size_t ws_size,
                              hipStream_t stream) {
  const float* x   = (const float*)d_in[0];
  const float* Win = (const float*)d_in[1];
  const float* bin = (const float*)d_in[2];
  const float* W0  = (const float*)d_in[3];
  const float* b0  = (const float*)d_in[4];
  const float* W1  = (const float*)d_in[5];
  const float* b1  = (const float*)d_in[6];
  const float* W2  = (const float*)d_in[7];
  const float* b2  = (const float*)d_in[8];
  float* out = (float*)d_out;
  half8* wsw2 = (half8*)d_ws;   // 512 KB: 256 hi frags + 256 lo frags

  pack_w2_kernel<<<dim3(64), dim3(256), 0, stream>>>(W2, wsw2);
  ncde_kernel<<<dim3(1024 / BR), dim3(NTHREADS), 0, stream>>>(
      x, Win, bin, W0, b0, W1, b1, W2, b2, wsw2, out);
}